// Round 3
// baseline (217.892 us; speedup 1.0000x reference)
//
#include <hip/hip_runtime.h>
#include <cmath>

#define T_LEN   480000
#define BATCH   64
#define CHUNK   16                       /* samples per thread */
#define WARM    32                       /* warm-up samples (pole^32 ~ 6e-13) */
#define TPB     256
#define TS      (TPB * CHUNK)            /* 4096 samples per tile */
#define TPR     ((T_LEN + TS - 1) / TS)  /* 118 tiles per row */
#define NLOAD_MAX (TS + WARM)
/* skew: +1 float per 32 -> 2-way bank alias max (free per m136) */
#define LDS_SLOTS (NLOAD_MAX + (NLOAD_MAX >> 5))  /* 4257 floats = 17.0 KB */

__device__ __forceinline__ int slot(int i) { return i + (i >> 5); }

__global__ __launch_bounds__(TPB) void allpass_kernel(
    const float* __restrict__ x, float* __restrict__ y,
    float B0, float B1, float B2, float A1, float A2)
{
    __shared__ float lds[LDS_SLOTS];
    const int tid  = threadIdx.x;
    const int row  = blockIdx.x / TPR;
    const int tb   = blockIdx.x % TPR;
    const int sbase = tb * TS;
    const int ns   = min(TS, T_LEN - sbase);      /* 4096, last tile 768 */
    const float* __restrict__ xr = x + (size_t)row * T_LEN + sbase;
    float* __restrict__ yr       = y + (size_t)row * T_LEN + sbase;

    /* ---- coalesced load of [sbase-WARM, sbase+ns) into skewed LDS ---- */
    const int nload = ns + WARM;                  /* multiple of 4 */
    for (int i4 = tid * 4; i4 < nload; i4 += TPB * 4) {
        float4 v;
        if (tb == 0 && i4 < WARM) {
            v = make_float4(0.f, 0.f, 0.f, 0.f);  /* zero state before t=0 */
        } else {
            v = *(const float4*)(xr - WARM + i4);
        }
        lds[slot(i4 + 0)] = v.x;
        lds[slot(i4 + 1)] = v.y;
        lds[slot(i4 + 2)] = v.z;
        lds[slot(i4 + 3)] = v.w;
    }
    __syncthreads();

    /* ---- per-thread recurrence: WARM warm-up + CHUNK real steps ---- */
    float yv[CHUNK];
    const int ls = tid * CHUNK;                   /* output-coord start */
    const bool active = (ls < ns);
    if (active) {
        float x1 = 0.f, x2 = 0.f, y1 = 0.f, y2 = 0.f;
        #pragma unroll
        for (int t = 0; t < WARM; ++t) {          /* load coords [ls, ls+32) */
            float xn = lds[slot(ls + t)];
            float u  = fmaf(B0, xn, fmaf(B1, x1, B2 * x2));
            float yn = fmaf(-A1, y1, fmaf(-A2, y2, u));
            x2 = x1; x1 = xn; y2 = y1; y1 = yn;
        }
        #pragma unroll
        for (int t = 0; t < CHUNK; ++t) {         /* load coords [ls+32, ls+48) */
            float xn = lds[slot(ls + WARM + t)];
            float u  = fmaf(B0, xn, fmaf(B1, x1, B2 * x2));
            float yn = fmaf(-A1, y1, fmaf(-A2, y2, u));
            yv[t] = yn;
            x2 = x1; x1 = xn; y2 = y1; y1 = yn;
        }
    }
    __syncthreads();                              /* all LDS x-reads done */

    /* ---- stage y through LDS (output coords) for coalesced stores ---- */
    if (active) {
        #pragma unroll
        for (int t = 0; t < CHUNK; ++t) lds[slot(ls + t)] = yv[t];
    }
    __syncthreads();

    for (int i4 = tid * 4; i4 < ns; i4 += TPB * 4) {
        float4 v;
        v.x = lds[slot(i4 + 0)];
        v.y = lds[slot(i4 + 1)];
        v.z = lds[slot(i4 + 2)];
        v.w = lds[slot(i4 + 3)];
        *(float4*)(yr + i4) = v;
    }
}

extern "C" void kernel_launch(void* const* d_in, const int* in_sizes, int n_in,
                              void* d_out, int out_size, void* d_ws, size_t ws_size,
                              hipStream_t stream) {
    const float* x = (const float*)d_in[0];
    float* y = (float*)d_out;

    const double sample_rate = 16000.0, central_freq = 4000.0, Q = 0.707;
    const double w0 = 2.0 * M_PI * central_freq / sample_rate;
    const double alpha = sin(w0) / (2.0 * Q);
    const double cw = cos(w0);
    const double a0 = 1.0 + alpha;
    const float B0 = (float)((1.0 - alpha) / a0);
    const float B1 = (float)((-2.0 * cw) / a0);
    const float B2 = (float)((1.0 + alpha) / a0);
    const float A1 = (float)((-2.0 * cw) / a0);
    const float A2 = (float)((1.0 - alpha) / a0);

    const int blocks = BATCH * TPR;   /* 7552 */
    allpass_kernel<<<blocks, TPB, 0, stream>>>(x, y, B0, B1, B2, A1, A2);
}

// Round 4
// 217.411 us; speedup vs baseline: 1.0022x; 1.0022x over previous
//
#include <hip/hip_runtime.h>
#include <cmath>

#define T_LEN   480000
#define BATCH   64
#define CHUNK   16                       /* samples per thread */
#define WARM    32                       /* warm-up samples (pole^32 ~ 6e-13) */
#define TPB     256
#define TS      (TPB * CHUNK)            /* 4096 samples per tile */
#define TPR     ((T_LEN + TS - 1) / TS)  /* 118 tiles per row */
#define NLOAD_MAX (TS + WARM)            /* 4128 */
/* quad skew: +4 floats per 32 -> every aligned float4 stays contiguous,
   and all three access patterns are exactly bank-uniform (8 lanes/quad). */
#define LDS_SLOTS (NLOAD_MAX + ((NLOAD_MAX >> 5) << 2))  /* 4644 = 18.6 KB */

__device__ __forceinline__ int slot4(int i) { return i + ((i >> 5) << 2); }

#define STEP(XN, YN)                                            \
    {                                                           \
        float u_ = fmaf(B0, (XN), fmaf(B1, x1, B2 * x2));       \
        (YN) = fmaf(-A1, y1, fmaf(-A2, y2, u_));                \
        x2 = x1; x1 = (XN); y2 = y1; y1 = (YN);                 \
    }

__global__ __launch_bounds__(TPB) void allpass_kernel(
    const float* __restrict__ x, float* __restrict__ y,
    float B0, float B1, float B2, float A1, float A2)
{
    __shared__ __align__(16) float lds[LDS_SLOTS];
    const int tid  = threadIdx.x;
    const int row  = blockIdx.x / TPR;
    const int tb   = blockIdx.x % TPR;
    const int sbase = tb * TS;
    const int ns   = min(TS, T_LEN - sbase);      /* 4096, last tile 768 */
    const float* __restrict__ xr = x + (size_t)row * T_LEN + sbase;
    float* __restrict__ yr       = y + (size_t)row * T_LEN + sbase;

    /* ---- coalesced load of [sbase-WARM, sbase+ns) into skewed LDS ---- */
    const int nload = ns + WARM;                  /* multiple of 4 */
    for (int i4 = tid * 4; i4 < nload; i4 += TPB * 4) {
        float4 v;
        if (tb == 0 && i4 < WARM) {
            v = make_float4(0.f, 0.f, 0.f, 0.f);  /* zero state before t=0 */
        } else {
            v = *(const float4*)(xr - WARM + i4);
        }
        *(float4*)&lds[slot4(i4)] = v;            /* ds_write_b128, uniform */
    }
    __syncthreads();

    /* ---- per-thread recurrence: WARM warm-up + CHUNK real steps ---- */
    float4 yq[CHUNK / 4];
    const int ls = tid * CHUNK;                   /* output-coord start */
    const bool active = (ls < ns);
    if (active) {
        float x1 = 0.f, x2 = 0.f, y1 = 0.f, y2 = 0.f;
        #pragma unroll
        for (int t4 = 0; t4 < WARM; t4 += 4) {    /* coords [ls, ls+32) */
            float4 xv = *(const float4*)&lds[slot4(ls + t4)];
            float t;
            STEP(xv.x, t); STEP(xv.y, t); STEP(xv.z, t); STEP(xv.w, t);
        }
        #pragma unroll
        for (int t4 = 0; t4 < CHUNK; t4 += 4) {   /* coords [ls+32, ls+48) */
            float4 xv = *(const float4*)&lds[slot4(ls + WARM + t4)];
            float4 yv;
            STEP(xv.x, yv.x); STEP(xv.y, yv.y);
            STEP(xv.z, yv.z); STEP(xv.w, yv.w);
            yq[t4 / 4] = yv;
        }
    }
    __syncthreads();                              /* all LDS x-reads done */

    /* ---- stage y through LDS (output coords) for coalesced stores ---- */
    if (active) {
        #pragma unroll
        for (int t4 = 0; t4 < CHUNK; t4 += 4)
            *(float4*)&lds[slot4(ls + t4)] = yq[t4 / 4];
    }
    __syncthreads();

    for (int i4 = tid * 4; i4 < ns; i4 += TPB * 4) {
        float4 v = *(const float4*)&lds[slot4(i4)];
        *(float4*)(yr + i4) = v;
    }
}

extern "C" void kernel_launch(void* const* d_in, const int* in_sizes, int n_in,
                              void* d_out, int out_size, void* d_ws, size_t ws_size,
                              hipStream_t stream) {
    const float* x = (const float*)d_in[0];
    float* y = (float*)d_out;

    const double sample_rate = 16000.0, central_freq = 4000.0, Q = 0.707;
    const double w0 = 2.0 * M_PI * central_freq / sample_rate;
    const double alpha = sin(w0) / (2.0 * Q);
    const double cw = cos(w0);
    const double a0 = 1.0 + alpha;
    const float B0 = (float)((1.0 - alpha) / a0);
    const float B1 = (float)((-2.0 * cw) / a0);
    const float B2 = (float)((1.0 + alpha) / a0);
    const float A1 = (float)((-2.0 * cw) / a0);
    const float A2 = (float)((1.0 - alpha) / a0);

    const int blocks = BATCH * TPR;   /* 7552 */
    allpass_kernel<<<blocks, TPB, 0, stream>>>(x, y, B0, B1, B2, A1, A2);
}